// Round 2
// baseline (260.338 us; speedup 1.0000x reference)
//
#include <hip/hip_runtime.h>
#include <math.h>

#define B_  64
#define L_  2048
#define DM  12
#define DI  24
#define DS  16
#define DC  4
#define DTR 1
#define T_  (B_ * L_)        // 131072 tokens
#define NCHUNK 16
#define CHUNK  128           // L_ / NCHUNK

// ---------------- ws layout (in floats) ----------------
// xi    : T_*DI   (post-conv, post-silu)
// zs    : T_*DI   (silu(z))
// delta : T_*DI
// Bm    : T_*DS
// Cm    : T_*DS
// ys    : T_*DI   (scan output)
// xf    : T_*DM   (|FFT(x)|)
// P     : B_*DI*NCHUNK*DS   (per-chunk prod of a)
// H     : B_*DI*NCHUNK*DS   (per-chunk local final h)
// H0    : B_*DI*NCHUNK*DS   (per-chunk initial h)
// part  : 512               (per-block partial sums of o3)
// total ~19.5M floats ~78MB

__device__ __forceinline__ float siluf(float v)  { return v / (1.0f + expf(-v)); }
__device__ __forceinline__ float softplusf(float v) {
    if (v > 20.0f)  return v;
    if (v < -20.0f) return expf(v);
    return log1pf(expf(v));
}
__device__ __forceinline__ float geluf(float v) {
    return 0.5f * v * (1.0f + erff(v * 0.70710678118654752440f));
}
__device__ __forceinline__ float eluf(float v) { return v > 0.0f ? v : expf(v) - 1.0f; }

// ============ K1: in_proj + depthwise causal conv + silu + x_proj + delta ============
__global__ __launch_bounds__(256) void k_proj(
    const float* __restrict__ x, const float* __restrict__ w_in,
    const float* __restrict__ conv_w, const float* __restrict__ conv_b,
    const float* __restrict__ xproj_w, const float* __restrict__ dt_w,
    const float* __restrict__ dt_b,
    float* __restrict__ xi_out, float* __restrict__ zs_out,
    float* __restrict__ delta_out, float* __restrict__ Bm_out,
    float* __restrict__ Cm_out)
{
    __shared__ float s_xi[256 + 3][DI + 1];   // +1 pad: stride-24 would be a 16-way bank conflict
    const int tid = threadIdx.x;
    const int b   = blockIdx.x >> 3;
    const int l0  = (blockIdx.x & 7) << 8;
    const int l   = l0 + tid;
    const int t   = b * L_ + l;

    float xv[DM];
#pragma unroll
    for (int d = 0; d < DM; ++d) xv[d] = x[t * DM + d];

    // z half of in_proj -> silu -> store
#pragma unroll
    for (int e = 0; e < DI; ++e) {
        float acc = 0.0f;
#pragma unroll
        for (int d = 0; d < DM; ++d) acc += xv[d] * w_in[(DI + e) * DM + d];
        zs_out[t * DI + e] = siluf(acc);
    }
    // xi half -> LDS (pre-conv)
#pragma unroll
    for (int e = 0; e < DI; ++e) {
        float acc = 0.0f;
#pragma unroll
        for (int d = 0; d < DM; ++d) acc += xv[d] * w_in[e * DM + d];
        s_xi[tid + 3][e] = acc;
    }
    // halo: 3 tokens before the segment (zero outside batch row)
    if (tid < 3) {
        const int lh = l0 - 3 + tid;
        if (lh < 0) {
            for (int e = 0; e < DI; ++e) s_xi[tid][e] = 0.0f;
        } else {
            const int th = b * L_ + lh;
            float xh[DM];
            for (int d = 0; d < DM; ++d) xh[d] = x[th * DM + d];
            for (int e = 0; e < DI; ++e) {
                float acc = 0.0f;
                for (int d = 0; d < DM; ++d) acc += xh[d] * w_in[e * DM + d];
                s_xi[tid][e] = acc;
            }
        }
    }
    __syncthreads();

    float xi[DI];
#pragma unroll
    for (int dch = 0; dch < DI; ++dch) {
        float acc = conv_b[dch];
#pragma unroll
        for (int k = 0; k < DC; ++k) acc += s_xi[tid + k][dch] * conv_w[dch * DC + k];
        xi[dch] = siluf(acc);
        xi_out[t * DI + dch] = xi[dch];
    }

    float dt = 0.0f;
#pragma unroll
    for (int d = 0; d < DI; ++d) dt += xi[d] * xproj_w[d];
#pragma unroll
    for (int e = 0; e < DS; ++e) {
        float accB = 0.0f, accC = 0.0f;
#pragma unroll
        for (int d = 0; d < DI; ++d) {
            accB += xi[d] * xproj_w[(1 + e) * DI + d];
            accC += xi[d] * xproj_w[(1 + DS + e) * DI + d];
        }
        Bm_out[t * DS + e] = accB;
        Cm_out[t * DS + e] = accC;
    }
#pragma unroll
    for (int d = 0; d < DI; ++d)
        delta_out[t * DI + d] = softplusf(dt * dt_w[d] + dt_b[d]);
}

// ============ K2: scan phase 1 — per-chunk local scan + product of a ============
__global__ __launch_bounds__(256) void k_scan1(
    const float* __restrict__ delta, const float* __restrict__ xi,
    const float* __restrict__ Bm, const float* __restrict__ A_log,
    float* __restrict__ P, float* __restrict__ H)
{
    const int tid = threadIdx.x;
    const int n   = tid & 15;
    const int g   = (blockIdx.x << 4) + (tid >> 4);  // 0..24575 = (b,d,c)
    const int c   = g & 15;
    const int d   = (g >> 4) % DI;
    const int b   = g / (16 * DI);
    const float An = -expf(A_log[d * DS + n]);
    float h = 0.0f, prod = 1.0f;
    const int tbase = b * L_ + c * CHUNK;
    for (int i = 0; i < CHUNK; ++i) {
        const int t = tbase + i;
        const float del = delta[t * DI + d];
        const float xiv = xi[t * DI + d];
        const float Bv  = Bm[t * DS + n];
        const float a = expf(del * An);
        h = a * h + del * xiv * Bv;
        prod *= a;
    }
    const int u = ((b * DI + d) * NCHUNK + c) * DS + n;
    P[u] = prod;
    H[u] = h;
}

// ============ K3: scan phase 2 — combine chunk summaries ============
__global__ __launch_bounds__(256) void k_scan2(
    const float* __restrict__ P, const float* __restrict__ H, float* __restrict__ H0)
{
    const int idx  = blockIdx.x * 256 + threadIdx.x;  // 24576 = (b*DI+d)*16 + n
    const int n    = idx & 15;
    const int rest = idx >> 4;
    float Hc = 0.0f;
    const int base = rest * NCHUNK * DS + n;
    for (int c = 0; c < NCHUNK; ++c) {
        const int u = base + c * DS;
        H0[u] = Hc;
        Hc = P[u] * Hc + H[u];
    }
}

// ============ K4: scan phase 3 — replay with correct h0, emit y ============
__global__ __launch_bounds__(256) void k_scan3(
    const float* __restrict__ delta, const float* __restrict__ xi,
    const float* __restrict__ Bm, const float* __restrict__ Cm,
    const float* __restrict__ H0, const float* __restrict__ A_log,
    float* __restrict__ ys)
{
    const int tid = threadIdx.x;
    const int n   = tid & 15;
    const int g   = (blockIdx.x << 4) + (tid >> 4);
    const int c   = g & 15;
    const int d   = (g >> 4) % DI;
    const int b   = g / (16 * DI);
    const float An = -expf(A_log[d * DS + n]);
    const int u = ((b * DI + d) * NCHUNK + c) * DS + n;
    float h = H0[u];
    const int tbase = b * L_ + c * CHUNK;
    for (int i = 0; i < CHUNK; ++i) {
        const int t = tbase + i;
        const float del = delta[t * DI + d];
        const float xiv = xi[t * DI + d];
        const float Bv  = Bm[t * DS + n];
        const float a = expf(del * An);
        h = a * h + del * xiv * Bv;
        float p = h * Cm[t * DS + n];
        p += __shfl_xor(p, 1);
        p += __shfl_xor(p, 2);
        p += __shfl_xor(p, 4);
        p += __shfl_xor(p, 8);
        if (n == 0) ys[t * DI + d] = p;
    }
}

// ============ K5: 2048-pt complex FFT per (b, dm), output |X| ============
__global__ __launch_bounds__(256) void k_fft(
    const float* __restrict__ x, float* __restrict__ xf)
{
    __shared__ float re[2048], im[2048], twr[1024], twi[1024];
    const int tid = threadIdx.x;
    const int b   = blockIdx.x / DM;
    const int dm  = blockIdx.x % DM;
    for (int j = tid; j < 1024; j += 256) {
        const float ang = -6.283185307179586f * (float)j * (1.0f / 2048.0f);
        float s, c;
        sincosf(ang, &s, &c);
        twr[j] = c; twi[j] = s;
    }
    for (int i = tid; i < 2048; i += 256) {
        const int r = (int)(__brev((unsigned)i) >> 21);
        re[r] = x[(b * L_ + i) * DM + dm];
        im[r] = 0.0f;
    }
    __syncthreads();
    for (int s = 1; s <= 11; ++s) {
        const int half  = 1 << (s - 1);
        const int tstep = 2048 >> s;
        for (int i = tid; i < 1024; i += 256) {
            const int j   = i & (half - 1);
            const int grp = i >> (s - 1);
            const int pos = (grp << s) + j;
            const float wr = twr[j * tstep], wi = twi[j * tstep];
            const float ar = re[pos + half], ai = im[pos + half];
            const float vr = wr * ar - wi * ai;
            const float vi = wr * ai + wi * ar;
            const float ur = re[pos], ui = im[pos];
            re[pos] = ur + vr;          im[pos] = ui + vi;
            re[pos + half] = ur - vr;   im[pos + half] = ui - vi;
        }
        __syncthreads();
    }
    for (int i = tid; i < 2048; i += 256) {
        const float a = re[i], bb = im[i];
        xf[(b * L_ + i) * DM + dm] = sqrtf(a * a + bb * bb);
    }
}

// ============ K6: gate + out_proj + LN + FFN + LN + CNN + head + partial sum ============
__global__ __launch_bounds__(256) void k_tail(
    const float* __restrict__ ys, const float* __restrict__ xi,
    const float* __restrict__ zs, const float* __restrict__ xf,
    const float* __restrict__ Dp, const float* __restrict__ out_w,
    const float* __restrict__ ln1_g, const float* __restrict__ ln1_b,
    const float* __restrict__ w1, const float* __restrict__ b1,
    const float* __restrict__ w2, const float* __restrict__ b2,
    const float* __restrict__ lng, const float* __restrict__ lnb,
    const float* __restrict__ cnn_w, const float* __restrict__ cnn_b,
    const float* __restrict__ l1w, const float* __restrict__ l1b,
    const float* __restrict__ l2w, const float* __restrict__ l2b,
    const float* __restrict__ l3w, const float* __restrict__ l3b,
    float* __restrict__ part)
{
    const int tid = threadIdx.x;
    const int b   = blockIdx.x >> 3;
    const int l   = ((blockIdx.x & 7) << 8) + tid;
    const int t   = b * L_ + l;

    float y[DI];
#pragma unroll
    for (int e = 0; e < DI; ++e)
        y[e] = (ys[t * DI + e] + xi[t * DI + e] * Dp[e]) * zs[t * DI + e];

    float m[DM];
#pragma unroll
    for (int j = 0; j < DM; ++j) {
        float acc = 0.0f;
#pragma unroll
        for (int e = 0; e < DI; ++e) acc += y[e] * out_w[j * DI + e];
        m[j] = acc;
    }
    // LN1
    float mean = 0.0f;
#pragma unroll
    for (int j = 0; j < DM; ++j) mean += m[j];
    mean *= (1.0f / DM);
    float var = 0.0f;
#pragma unroll
    for (int j = 0; j < DM; ++j) { const float dv = m[j] - mean; var += dv * dv; }
    var *= (1.0f / DM);
    const float inv1 = rsqrtf(var + 1e-12f);
    float h[DM];
#pragma unroll
    for (int j = 0; j < DM; ++j) h[j] = (m[j] - mean) * inv1 * ln1_g[j] + ln1_b[j];

    // FFN
    float ff[4 * DM];
#pragma unroll
    for (int e = 0; e < 4 * DM; ++e) {
        float acc = b1[e];
#pragma unroll
        for (int j = 0; j < DM; ++j) acc += h[j] * w1[e * DM + j];
        ff[e] = geluf(acc);
    }
    float f2[DM];
#pragma unroll
    for (int j = 0; j < DM; ++j) {
        float acc = b2[j];
#pragma unroll
        for (int e = 0; e < 4 * DM; ++e) acc += ff[e] * w2[j * (4 * DM) + e];
        f2[j] = acc + h[j];
    }
    // LN2 -> x_mamba
    mean = 0.0f;
#pragma unroll
    for (int j = 0; j < DM; ++j) mean += f2[j];
    mean *= (1.0f / DM);
    var = 0.0f;
#pragma unroll
    for (int j = 0; j < DM; ++j) { const float dv = f2[j] - mean; var += dv * dv; }
    var *= (1.0f / DM);
    const float inv2 = rsqrtf(var + 1e-12f);
    float xm[DM];
#pragma unroll
    for (int j = 0; j < DM; ++j) xm[j] = (f2[j] - mean) * inv2 * lng[j] + lnb[j];

    // CNN over xf (padding 1 both sides, per batch row)
    float xfm[DM], xf0[DM], xfp[DM];
#pragma unroll
    for (int i = 0; i < DM; ++i) {
        xfm[i] = (l == 0)      ? 0.0f : xf[(t - 1) * DM + i];
        xf0[i] = xf[t * DM + i];
        xfp[i] = (l == L_ - 1) ? 0.0f : xf[(t + 1) * DM + i];
    }
    float xc[DM];
#pragma unroll
    for (int o = 0; o < DM; ++o) {
        float acc = cnn_b[o];
#pragma unroll
        for (int i = 0; i < DM; ++i) {
            const int wb = (o * DM + i) * 3;
            acc += xfm[i] * cnn_w[wb] + xf0[i] * cnn_w[wb + 1] + xfp[i] * cnn_w[wb + 2];
        }
        xc[o] = acc;
    }

    // head: comb = [xm, xc]
    float o1[DM];
#pragma unroll
    for (int d = 0; d < DM; ++d) {
        float acc = l1b[d];
#pragma unroll
        for (int e = 0; e < DM; ++e) acc += xm[e] * l1w[d * (2 * DM) + e];
#pragma unroll
        for (int e = 0; e < DM; ++e) acc += xc[e] * l1w[d * (2 * DM) + DM + e];
        o1[d] = eluf(acc);
    }
    float o2[20];
#pragma unroll
    for (int e = 0; e < 20; ++e) {
        float acc = l2b[e];
#pragma unroll
        for (int d = 0; d < DM; ++d) acc += o1[d] * l2w[e * DM + d];
        o2[e] = acc;
    }
    float o3 = l3b[0];
#pragma unroll
    for (int e = 0; e < 20; ++e) o3 += o2[e] * l3w[e];

    // block reduction of o3
    __shared__ float sred[256];
    sred[tid] = o3;
    __syncthreads();
    for (int s = 128; s > 0; s >>= 1) {
        if (tid < s) sred[tid] += sred[tid + s];
        __syncthreads();
    }
    if (tid == 0) part[blockIdx.x] = sred[0];
}

// ============ K7: final per-batch mean + sigmoid ============
__global__ void k_final(const float* __restrict__ part, float* __restrict__ out)
{
    const int b = threadIdx.x;
    if (b < B_) {
        float s = 0.0f;
        for (int i = 0; i < 8; ++i) s += part[b * 8 + i];
        s *= (1.0f / (float)L_);
        out[b] = 1.0f / (1.0f + expf(-s));
    }
}

extern "C" void kernel_launch(void* const* d_in, const int* in_sizes, int n_in,
                              void* d_out, int out_size, void* d_ws, size_t ws_size,
                              hipStream_t stream)
{
    const float* x        = (const float*)d_in[0];
    const float* in_w     = (const float*)d_in[1];
    const float* conv_w   = (const float*)d_in[2];
    const float* conv_b   = (const float*)d_in[3];
    const float* xproj_w  = (const float*)d_in[4];
    const float* dt_w     = (const float*)d_in[5];
    const float* dt_b     = (const float*)d_in[6];
    const float* A_log    = (const float*)d_in[7];
    const float* Dp       = (const float*)d_in[8];
    const float* out_w    = (const float*)d_in[9];
    const float* ln1_g    = (const float*)d_in[10];
    const float* ln1_b    = (const float*)d_in[11];
    const float* ffn_w1   = (const float*)d_in[12];
    const float* ffn_b1   = (const float*)d_in[13];
    const float* ffn_w2   = (const float*)d_in[14];
    const float* ffn_b2   = (const float*)d_in[15];
    const float* ffn_ln_g = (const float*)d_in[16];
    const float* ffn_ln_b = (const float*)d_in[17];
    const float* cnn_w    = (const float*)d_in[18];
    const float* cnn_b    = (const float*)d_in[19];
    const float* l1w      = (const float*)d_in[20];
    const float* l1b      = (const float*)d_in[21];
    const float* l2w      = (const float*)d_in[22];
    const float* l2b      = (const float*)d_in[23];
    const float* l3w      = (const float*)d_in[24];
    const float* l3b      = (const float*)d_in[25];
    float* out = (float*)d_out;

    float* ws = (float*)d_ws;
    const size_t nTDI = (size_t)T_ * DI;
    const size_t nTDS = (size_t)T_ * DS;
    const size_t nTDM = (size_t)T_ * DM;
    const size_t nU   = (size_t)B_ * DI * NCHUNK * DS;
    float* w_xi    = ws;
    float* w_zs    = w_xi + nTDI;
    float* w_delta = w_zs + nTDI;
    float* w_Bm    = w_delta + nTDI;
    float* w_Cm    = w_Bm + nTDS;
    float* w_ys    = w_Cm + nTDS;
    float* w_xf    = w_ys + nTDI;
    float* w_P     = w_xf + nTDM;
    float* w_H     = w_P + nU;
    float* w_H0    = w_H + nU;
    float* w_part  = w_H0 + nU;

    k_proj<<<512, 256, 0, stream>>>(x, in_w, conv_w, conv_b, xproj_w, dt_w, dt_b,
                                    w_xi, w_zs, w_delta, w_Bm, w_Cm);
    k_fft<<<B_ * DM, 256, 0, stream>>>(x, w_xf);
    k_scan1<<<1536, 256, 0, stream>>>(w_delta, w_xi, w_Bm, A_log, w_P, w_H);
    k_scan2<<<96, 256, 0, stream>>>(w_P, w_H, w_H0);
    k_scan3<<<1536, 256, 0, stream>>>(w_delta, w_xi, w_Bm, w_Cm, w_H0, A_log, w_ys);
    k_tail<<<512, 256, 0, stream>>>(w_ys, w_xi, w_zs, w_xf, Dp, out_w,
                                    ln1_g, ln1_b, ffn_w1, ffn_b1, ffn_w2, ffn_b2,
                                    ffn_ln_g, ffn_ln_b, cnn_w, cnn_b,
                                    l1w, l1b, l2w, l2b, l3w, l3b, w_part);
    k_final<<<1, 64, 0, stream>>>(w_part, out);
}

// Round 3
// 232.306 us; speedup vs baseline: 1.1207x; 1.1207x over previous
//
#include <hip/hip_runtime.h>
#include <math.h>

#define B_  64
#define L_  2048
#define DM  12
#define DI  24
#define DS  16
#define DC  4
#define DTR 1
#define T_  (B_ * L_)        // 131072 tokens
#define NCHUNK 16
#define CHUNK  128           // L_ / NCHUNK

// ---------------- ws layout (in floats) — identical footprint to round 2 ----------------
// xi    : T_*DI   (post-conv, post-silu)
// zs    : T_*DI   (silu(z))
// delta : T_*DI
// Bm    : T_*DS
// Cm    : T_*DS
// y     : T_*DI   (scan output, GATED: (ys + xi*Dp)*zs)
// xf    : T_*DM   (|FFT(x)|)
// P     : B_*DI*NCHUNK*DS
// H     : B_*DI*NCHUNK*DS
// H0    : B_*DI*NCHUNK*DS
// part  : 512

__device__ __forceinline__ float siluf(float v)  { return v / (1.0f + expf(-v)); }
__device__ __forceinline__ float softplusf(float v) {
    if (v > 20.0f)  return v;
    if (v < -20.0f) return expf(v);
    return log1pf(expf(v));
}
__device__ __forceinline__ float geluf(float v) {
    return 0.5f * v * (1.0f + erff(v * 0.70710678118654752440f));
}
__device__ __forceinline__ float eluf(float v) { return v > 0.0f ? v : expf(v) - 1.0f; }

// ============ K1: in_proj + depthwise causal conv + silu + x_proj + delta ============
__global__ __launch_bounds__(256) void k_proj(
    const float* __restrict__ x, const float* __restrict__ w_in,
    const float* __restrict__ conv_w, const float* __restrict__ conv_b,
    const float* __restrict__ xproj_w, const float* __restrict__ dt_w,
    const float* __restrict__ dt_b,
    float* __restrict__ xi_out, float* __restrict__ zs_out,
    float* __restrict__ delta_out, float* __restrict__ Bm_out,
    float* __restrict__ Cm_out)
{
    __shared__ float s_xi[256 + 3][DI + 1];
    const int tid = threadIdx.x;
    const int b   = blockIdx.x >> 3;
    const int l0  = (blockIdx.x & 7) << 8;
    const int l   = l0 + tid;
    const int t   = b * L_ + l;

    float xv[DM];
#pragma unroll
    for (int d = 0; d < DM; ++d) xv[d] = x[t * DM + d];

#pragma unroll
    for (int e = 0; e < DI; ++e) {
        float acc = 0.0f;
#pragma unroll
        for (int d = 0; d < DM; ++d) acc += xv[d] * w_in[(DI + e) * DM + d];
        zs_out[t * DI + e] = siluf(acc);
    }
#pragma unroll
    for (int e = 0; e < DI; ++e) {
        float acc = 0.0f;
#pragma unroll
        for (int d = 0; d < DM; ++d) acc += xv[d] * w_in[e * DM + d];
        s_xi[tid + 3][e] = acc;
    }
    if (tid < 3) {
        const int lh = l0 - 3 + tid;
        if (lh < 0) {
            for (int e = 0; e < DI; ++e) s_xi[tid][e] = 0.0f;
        } else {
            const int th = b * L_ + lh;
            float xh[DM];
            for (int d = 0; d < DM; ++d) xh[d] = x[th * DM + d];
            for (int e = 0; e < DI; ++e) {
                float acc = 0.0f;
                for (int d = 0; d < DM; ++d) acc += xh[d] * w_in[e * DM + d];
                s_xi[tid][e] = acc;
            }
        }
    }
    __syncthreads();

    float xi[DI];
#pragma unroll
    for (int dch = 0; dch < DI; ++dch) {
        float acc = conv_b[dch];
#pragma unroll
        for (int k = 0; k < DC; ++k) acc += s_xi[tid + k][dch] * conv_w[dch * DC + k];
        xi[dch] = siluf(acc);
        xi_out[t * DI + dch] = xi[dch];
    }

    float dt = 0.0f;
#pragma unroll
    for (int d = 0; d < DI; ++d) dt += xi[d] * xproj_w[d];
#pragma unroll
    for (int e = 0; e < DS; ++e) {
        float accB = 0.0f, accC = 0.0f;
#pragma unroll
        for (int d = 0; d < DI; ++d) {
            accB += xi[d] * xproj_w[(1 + e) * DI + d];
            accC += xi[d] * xproj_w[(1 + DS + e) * DI + d];
        }
        Bm_out[t * DS + e] = accB;
        Cm_out[t * DS + e] = accC;
    }
#pragma unroll
    for (int d = 0; d < DI; ++d)
        delta_out[t * DI + d] = softplusf(dt * dt_w[d] + dt_b[d]);
}

// ============ S1: per-chunk local scan, LDS-staged (block = (b,c), 384 thr = (d,n)) ============
__global__ __launch_bounds__(384) void k_scan1(
    const float* __restrict__ delta, const float* __restrict__ xi,
    const float* __restrict__ Bm, const float* __restrict__ A_log,
    float* __restrict__ P, float* __restrict__ H)
{
    __shared__ float s_dx[CHUNK * DI * 2];   // interleaved {delta, xi} per (i,d)  24 KB
    __shared__ float s_b[CHUNK * DS];        // Bm per (i,n)                        8 KB
    const int tid = threadIdx.x;
    const int b   = blockIdx.x / NCHUNK;
    const int c   = blockIdx.x % NCHUNK;
    const int t0  = b * L_ + c * CHUNK;

    const float* gD = delta + (size_t)t0 * DI;
    const float* gX = xi    + (size_t)t0 * DI;
    const float* gB = Bm    + (size_t)t0 * DS;
    for (int j = tid; j < CHUNK * DI; j += 384) {
        s_dx[2 * j]     = gD[j];
        s_dx[2 * j + 1] = gX[j];
    }
    for (int j = tid; j < CHUNK * DS; j += 384) s_b[j] = gB[j];

    const int d = tid >> 4;
    const int n = tid & 15;
    const float An = -expf(A_log[tid]);   // A_log[d*DS+n] == A_log[tid]
    __syncthreads();

    float h = 0.0f, prod = 1.0f;
    const float2* s_dx2 = (const float2*)s_dx;
#pragma unroll 4
    for (int i = 0; i < CHUNK; ++i) {
        const float2 dx = s_dx2[i * DI + d];
        const float Bv  = s_b[i * DS + n];
        const float a = expf(dx.x * An);
        h = a * h + dx.x * dx.y * Bv;
        prod *= a;
    }
    const int u = ((b * DI + d) * NCHUNK + c) * DS + n;
    P[u] = prod;
    H[u] = h;
}

// ============ S2: combine chunk summaries ============
__global__ __launch_bounds__(256) void k_scan2(
    const float* __restrict__ P, const float* __restrict__ H, float* __restrict__ H0)
{
    const int idx  = blockIdx.x * 256 + threadIdx.x;  // 24576 = (b*DI+d)*16 + n
    const int n    = idx & 15;
    const int rest = idx >> 4;
    float Hc = 0.0f;
    const int base = rest * NCHUNK * DS + n;
    for (int c = 0; c < NCHUNK; ++c) {
        const int u = base + c * DS;
        H0[u] = Hc;
        Hc = P[u] * Hc + H[u];
    }
}

// ============ S3: replay with h0, emit GATED y = (ys + xi*Dp)*zs, LDS-staged ============
__global__ __launch_bounds__(384) void k_scan3(
    const float* __restrict__ delta, const float* __restrict__ xi,
    const float* __restrict__ Bm, const float* __restrict__ Cm,
    const float* __restrict__ zs, const float* __restrict__ Dp,
    const float* __restrict__ H0, const float* __restrict__ A_log,
    float* __restrict__ y_out)
{
    __shared__ float s_dx[CHUNK * DI * 2];   // 24 KB
    __shared__ float s_bc[CHUNK * DS * 2];   // interleaved {Bm, Cm}  16 KB
    __shared__ float s_y[CHUNK * DI];        // 12 KB
    __shared__ float s_Dp[DI];
    const int tid = threadIdx.x;
    const int b   = blockIdx.x / NCHUNK;
    const int c   = blockIdx.x % NCHUNK;
    const int t0  = b * L_ + c * CHUNK;

    const float* gD = delta + (size_t)t0 * DI;
    const float* gX = xi    + (size_t)t0 * DI;
    const float* gB = Bm    + (size_t)t0 * DS;
    const float* gC = Cm    + (size_t)t0 * DS;
    for (int j = tid; j < CHUNK * DI; j += 384) {
        s_dx[2 * j]     = gD[j];
        s_dx[2 * j + 1] = gX[j];
    }
    for (int j = tid; j < CHUNK * DS; j += 384) {
        s_bc[2 * j]     = gB[j];
        s_bc[2 * j + 1] = gC[j];
    }
    if (tid < DI) s_Dp[tid] = Dp[tid];

    const int d = tid >> 4;
    const int n = tid & 15;
    const float An = -expf(A_log[tid]);
    const int u = ((b * DI + d) * NCHUNK + c) * DS + n;
    float h = H0[u];
    __syncthreads();

    const float2* s_dx2 = (const float2*)s_dx;
    const float2* s_bc2 = (const float2*)s_bc;
#pragma unroll 4
    for (int i = 0; i < CHUNK; ++i) {
        const float2 dx = s_dx2[i * DI + d];
        const float2 bc = s_bc2[i * DS + n];
        const float a = expf(dx.x * An);
        h = a * h + dx.x * dx.y * bc.x;
        float p = h * bc.y;
        p += __shfl_xor(p, 1);
        p += __shfl_xor(p, 2);
        p += __shfl_xor(p, 4);
        p += __shfl_xor(p, 8);
        if (n == 0) s_y[i * DI + d] = p;
    }
    __syncthreads();

    // coalesced write-out with fused gate: y = (ys + xi*Dp) * zs
    const float* gZ = zs + (size_t)t0 * DI;
    float* gY = y_out + (size_t)t0 * DI;
    for (int j = tid; j < CHUNK * DI; j += 384) {
        const int d2 = j % DI;
        const float v = (s_y[j] + s_dx[2 * j + 1] * s_Dp[d2]) * gZ[j];
        gY[j] = v;
    }
}

// ============ K5: 2048-pt complex FFT per (b, dm), output |X| ============
__global__ __launch_bounds__(256) void k_fft(
    const float* __restrict__ x, float* __restrict__ xf)
{
    __shared__ float re[2048], im[2048], twr[1024], twi[1024];
    const int tid = threadIdx.x;
    const int b   = blockIdx.x / DM;
    const int dm  = blockIdx.x % DM;
    for (int j = tid; j < 1024; j += 256) {
        const float ang = -6.283185307179586f * (float)j * (1.0f / 2048.0f);
        float s, c;
        sincosf(ang, &s, &c);
        twr[j] = c; twi[j] = s;
    }
    for (int i = tid; i < 2048; i += 256) {
        const int r = (int)(__brev((unsigned)i) >> 21);
        re[r] = x[(b * L_ + i) * DM + dm];
        im[r] = 0.0f;
    }
    __syncthreads();
    for (int s = 1; s <= 11; ++s) {
        const int half  = 1 << (s - 1);
        const int tstep = 2048 >> s;
        for (int i = tid; i < 1024; i += 256) {
            const int j   = i & (half - 1);
            const int grp = i >> (s - 1);
            const int pos = (grp << s) + j;
            const float wr = twr[j * tstep], wi = twi[j * tstep];
            const float ar = re[pos + half], ai = im[pos + half];
            const float vr = wr * ar - wi * ai;
            const float vi = wr * ai + wi * ar;
            const float ur = re[pos], ui = im[pos];
            re[pos] = ur + vr;          im[pos] = ui + vi;
            re[pos + half] = ur - vr;   im[pos + half] = ui - vi;
        }
        __syncthreads();
    }
    for (int i = tid; i < 2048; i += 256) {
        const float a = re[i], bb = im[i];
        xf[(b * L_ + i) * DM + dm] = sqrtf(a * a + bb * bb);
    }
}

// ============ K6: out_proj + LN + FFN + LN + CNN + head + partial sum ============
__global__ __launch_bounds__(256) void k_tail(
    const float* __restrict__ yg, const float* __restrict__ xf,
    const float* __restrict__ out_w,
    const float* __restrict__ ln1_g, const float* __restrict__ ln1_b,
    const float* __restrict__ w1, const float* __restrict__ b1,
    const float* __restrict__ w2, const float* __restrict__ b2,
    const float* __restrict__ lng, const float* __restrict__ lnb,
    const float* __restrict__ cnn_w, const float* __restrict__ cnn_b,
    const float* __restrict__ l1w, const float* __restrict__ l1b,
    const float* __restrict__ l2w, const float* __restrict__ l2b,
    const float* __restrict__ l3w, const float* __restrict__ l3b,
    float* __restrict__ part)
{
    const int tid = threadIdx.x;
    const int b   = blockIdx.x >> 3;
    const int l   = ((blockIdx.x & 7) << 8) + tid;
    const int t   = b * L_ + l;

    float y[DI];
#pragma unroll
    for (int e = 0; e < DI; ++e) y[e] = yg[t * DI + e];

    float m[DM];
#pragma unroll
    for (int j = 0; j < DM; ++j) {
        float acc = 0.0f;
#pragma unroll
        for (int e = 0; e < DI; ++e) acc += y[e] * out_w[j * DI + e];
        m[j] = acc;
    }
    float mean = 0.0f;
#pragma unroll
    for (int j = 0; j < DM; ++j) mean += m[j];
    mean *= (1.0f / DM);
    float var = 0.0f;
#pragma unroll
    for (int j = 0; j < DM; ++j) { const float dv = m[j] - mean; var += dv * dv; }
    var *= (1.0f / DM);
    const float inv1 = rsqrtf(var + 1e-12f);
    float h[DM];
#pragma unroll
    for (int j = 0; j < DM; ++j) h[j] = (m[j] - mean) * inv1 * ln1_g[j] + ln1_b[j];

    float ff[4 * DM];
#pragma unroll
    for (int e = 0; e < 4 * DM; ++e) {
        float acc = b1[e];
#pragma unroll
        for (int j = 0; j < DM; ++j) acc += h[j] * w1[e * DM + j];
        ff[e] = geluf(acc);
    }
    float f2[DM];
#pragma unroll
    for (int j = 0; j < DM; ++j) {
        float acc = b2[j];
#pragma unroll
        for (int e = 0; e < 4 * DM; ++e) acc += ff[e] * w2[j * (4 * DM) + e];
        f2[j] = acc + h[j];
    }
    mean = 0.0f;
#pragma unroll
    for (int j = 0; j < DM; ++j) mean += f2[j];
    mean *= (1.0f / DM);
    var = 0.0f;
#pragma unroll
    for (int j = 0; j < DM; ++j) { const float dv = f2[j] - mean; var += dv * dv; }
    var *= (1.0f / DM);
    const float inv2 = rsqrtf(var + 1e-12f);
    float xm[DM];
#pragma unroll
    for (int j = 0; j < DM; ++j) xm[j] = (f2[j] - mean) * inv2 * lng[j] + lnb[j];

    float xfm[DM], xf0[DM], xfp[DM];
#pragma unroll
    for (int i = 0; i < DM; ++i) {
        xfm[i] = (l == 0)      ? 0.0f : xf[(t - 1) * DM + i];
        xf0[i] = xf[t * DM + i];
        xfp[i] = (l == L_ - 1) ? 0.0f : xf[(t + 1) * DM + i];
    }
    float xc[DM];
#pragma unroll
    for (int o = 0; o < DM; ++o) {
        float acc = cnn_b[o];
#pragma unroll
        for (int i = 0; i < DM; ++i) {
            const int wb = (o * DM + i) * 3;
            acc += xfm[i] * cnn_w[wb] + xf0[i] * cnn_w[wb + 1] + xfp[i] * cnn_w[wb + 2];
        }
        xc[o] = acc;
    }

    float o1[DM];
#pragma unroll
    for (int d = 0; d < DM; ++d) {
        float acc = l1b[d];
#pragma unroll
        for (int e = 0; e < DM; ++e) acc += xm[e] * l1w[d * (2 * DM) + e];
#pragma unroll
        for (int e = 0; e < DM; ++e) acc += xc[e] * l1w[d * (2 * DM) + DM + e];
        o1[d] = eluf(acc);
    }
    float o2[20];
#pragma unroll
    for (int e = 0; e < 20; ++e) {
        float acc = l2b[e];
#pragma unroll
        for (int d = 0; d < DM; ++d) acc += o1[d] * l2w[e * DM + d];
        o2[e] = acc;
    }
    float o3 = l3b[0];
#pragma unroll
    for (int e = 0; e < 20; ++e) o3 += o2[e] * l3w[e];

    __shared__ float sred[256];
    sred[tid] = o3;
    __syncthreads();
    for (int s = 128; s > 0; s >>= 1) {
        if (tid < s) sred[tid] += sred[tid + s];
        __syncthreads();
    }
    if (tid == 0) part[blockIdx.x] = sred[0];
}

// ============ K7: final per-batch mean + sigmoid ============
__global__ void k_final(const float* __restrict__ part, float* __restrict__ out)
{
    const int b = threadIdx.x;
    if (b < B_) {
        float s = 0.0f;
        for (int i = 0; i < 8; ++i) s += part[b * 8 + i];
        s *= (1.0f / (float)L_);
        out[b] = 1.0f / (1.0f + expf(-s));
    }
}

extern "C" void kernel_launch(void* const* d_in, const int* in_sizes, int n_in,
                              void* d_out, int out_size, void* d_ws, size_t ws_size,
                              hipStream_t stream)
{
    const float* x        = (const float*)d_in[0];
    const float* in_w     = (const float*)d_in[1];
    const float* conv_w   = (const float*)d_in[2];
    const float* conv_b   = (const float*)d_in[3];
    const float* xproj_w  = (const float*)d_in[4];
    const float* dt_w     = (const float*)d_in[5];
    const float* dt_b     = (const float*)d_in[6];
    const float* A_log    = (const float*)d_in[7];
    const float* Dp       = (const float*)d_in[8];
    const float* out_w    = (const float*)d_in[9];
    const float* ln1_g    = (const float*)d_in[10];
    const float* ln1_b    = (const float*)d_in[11];
    const float* ffn_w1   = (const float*)d_in[12];
    const float* ffn_b1   = (const float*)d_in[13];
    const float* ffn_w2   = (const float*)d_in[14];
    const float* ffn_b2   = (const float*)d_in[15];
    const float* ffn_ln_g = (const float*)d_in[16];
    const float* ffn_ln_b = (const float*)d_in[17];
    const float* cnn_w    = (const float*)d_in[18];
    const float* cnn_b    = (const float*)d_in[19];
    const float* l1w      = (const float*)d_in[20];
    const float* l1b      = (const float*)d_in[21];
    const float* l2w      = (const float*)d_in[22];
    const float* l2b      = (const float*)d_in[23];
    const float* l3w      = (const float*)d_in[24];
    const float* l3b      = (const float*)d_in[25];
    float* out = (float*)d_out;

    float* ws = (float*)d_ws;
    const size_t nTDI = (size_t)T_ * DI;
    const size_t nTDS = (size_t)T_ * DS;
    const size_t nTDM = (size_t)T_ * DM;
    const size_t nU   = (size_t)B_ * DI * NCHUNK * DS;
    float* w_xi    = ws;
    float* w_zs    = w_xi + nTDI;
    float* w_delta = w_zs + nTDI;
    float* w_Bm    = w_delta + nTDI;
    float* w_Cm    = w_Bm + nTDS;
    float* w_y     = w_Cm + nTDS;
    float* w_xf    = w_y + nTDI;
    float* w_P     = w_xf + nTDM;
    float* w_H     = w_P + nU;
    float* w_H0    = w_H + nU;
    float* w_part  = w_H0 + nU;

    k_proj<<<512, 256, 0, stream>>>(x, in_w, conv_w, conv_b, xproj_w, dt_w, dt_b,
                                    w_xi, w_zs, w_delta, w_Bm, w_Cm);
    k_fft<<<B_ * DM, 256, 0, stream>>>(x, w_xf);
    k_scan1<<<B_ * NCHUNK, 384, 0, stream>>>(w_delta, w_xi, w_Bm, A_log, w_P, w_H);
    k_scan2<<<96, 256, 0, stream>>>(w_P, w_H, w_H0);
    k_scan3<<<B_ * NCHUNK, 384, 0, stream>>>(w_delta, w_xi, w_Bm, w_Cm, w_zs, Dp,
                                             w_H0, A_log, w_y);
    k_tail<<<512, 256, 0, stream>>>(w_y, w_xf, out_w,
                                    ln1_g, ln1_b, ffn_w1, ffn_b1, ffn_w2, ffn_b2,
                                    ffn_ln_g, ffn_ln_b, cnn_w, cnn_b,
                                    l1w, l1b, l2w, l2b, l3w, l3b, w_part);
    k_final<<<1, 64, 0, stream>>>(w_part, out);
}